// Round 6
// baseline (391.097 us; speedup 1.0000x reference)
//
#include <hip/hip_runtime.h>
#include <hip/hip_bf16.h>

#define N_NODES 50000
#define N_EDGES 1600000
#define HEADS 8
#define HDIM 16
#define D1 128   // HEADS*HDIM
#define NEG_SLOPE 0.2f
#define RTILES 3125    // 50000/16
#define NB 196         // dst buckets (dst>>8), 49999>>8 = 195
#define BCAP 12288     // per-bucket capacity (avg fill 8163 -> huge margin)
#define B1BLK 320      // bucket1 blocks
#define EPB1 5000      // edges per bucket1 block (320*5000 = 1.6M)

typedef short short8 __attribute__((ext_vector_type(8)));
typedef float f32x4 __attribute__((ext_vector_type(4)));
typedef _Float16 half8 __attribute__((ext_vector_type(8)));
typedef unsigned char uchar;

// ---- dtype helpers (isf32: 1 = buffers are fp32, 0 = bf16) ----
__device__ __forceinline__ float bf2f(ushort u) {
    union { unsigned u; float f; } x; x.u = ((unsigned)u) << 16; return x.f;
}
__device__ __forceinline__ ushort f2bf(float f) {
    union { float f; unsigned u; } x; x.f = f;
    unsigned r = x.u + 0x7FFF + ((x.u >> 16) & 1);   // RNE
    return (ushort)(r >> 16);
}
__device__ __forceinline__ float ldf(const void* p, size_t i, int isf32) {
    return isf32 ? ((const float*)p)[i] : bf2f(((const ushort*)p)[i]);
}
__device__ __forceinline__ void splitbf(float f, ushort& hi, ushort& lo) {
    unsigned u = __float_as_uint(f);
    unsigned uh = u & 0xFFFF0000u;
    hi = (ushort)(uh >> 16);
    lo = f2bf(f - __uint_as_float(uh));
}

// ---------------- workspace layout (bytes) ----------------
#define O_ROWPTR   0            // int[50001]
#define O_GCUR     200064       // int[196] per-bucket cursors
#define O_BBASE    400128       // int[257] bucket bases
#define O_FLAGS    602240
#define O_ESRC     2202624      // ushort[1600000] CSR edge srcs
#define O_W1HI     5402624      // 144x256 bf16
#define O_W1LO     5476352
#define O_W2HI     5550080      // 144x128 bf16
#define O_W2LO     5586944
#define O_B1F      5623808
#define O_B2F      5624320
#define O_FEATG    5624832      // fp16 [N][128] layer-1 features
#define O_EL       18424832
#define O_ER       20024832
#define O_FEATG2   21624832     // fp16 [N][128] layer-2 features
#define O_EL2      34424832
#define O_ER2      36024832
// end: 37624832 (37.6 MB)
// alias inside O_FEATG2 (12.8 MB), dead before agg1m writes featg2:
#define O_PKBUF    O_FEATG2     // uint[196][12288] = 9.63 MB packed bucketed edges

// ================= device helpers =================

// ---- phase A: dtype detect (block 0) + zero bucket cursors (block 1) ----
__global__ __launch_bounds__(256) void k_detect(const ushort* __restrict__ w1, int* __restrict__ flags,
                                                int* __restrict__ gcur) {
    __shared__ int sm[256];
    int t = threadIdx.x;
    if (blockIdx.x == 1) {
        if (t < NB) gcur[t] = 0;
        return;
    }
    int cnt = 0;
    for (int i = t; i < 32768; i += 256) {
        int e = (w1[i] >> 7) & 0xFF;
        if (e >= 0xC8) cnt++;
    }
    sm[t] = cnt; __syncthreads();
    for (int off = 128; off > 0; off >>= 1) {
        if (t < off) sm[t] += sm[t + off];
        __syncthreads();
    }
    if (t == 0) flags[0] = (sm[0] > 0) ? 1 : 0;
}

// W -> whi/wlo bf16 [144][K] transposed (rows 0..127 = W cols, 128..135 = W@al, 136..143 = W@ar)
__device__ __forceinline__ void wprep_elem(const void* W, const void* al, const void* ar,
                                           int K, int kshift, ushort* whi, ushort* wlo,
                                           int isf32, int idx) {
    if (idx >= 144 * K) return;
    int n = idx >> kshift, k = idx & (K - 1);
    float f;
    if (n < 128) {
        f = ldf(W, (size_t)k * 128 + n, isf32);
    } else if (n < 136) {
        int h = n - 128;
        f = 0.f;
#pragma unroll
        for (int d = 0; d < HDIM; ++d)
            f = fmaf(ldf(W, (size_t)k * 128 + h * 16 + d, isf32), ldf(al, h * 16 + d, isf32), f);
    } else {
        int h = n - 136;
        f = 0.f;
#pragma unroll
        for (int d = 0; d < HDIM; ++d)
            f = fmaf(ldf(W, (size_t)k * 128 + h * 16 + d, isf32), ldf(ar, h * 16 + d, isf32), f);
    }
    ushort hi = f2bf(f);
    wlo[n * K + k] = f2bf(f - bf2f(hi));
    whi[n * K + k] = hi;
}

// ---- phase B: weight prep ----
__global__ __launch_bounds__(256) void k_wprep(const void* __restrict__ W1, const void* __restrict__ al1,
                                               const void* __restrict__ ar1, const void* __restrict__ b1,
                                               const void* __restrict__ W2, const void* __restrict__ al2,
                                               const void* __restrict__ ar2, const void* __restrict__ b2,
                                               ushort* __restrict__ w1hi, ushort* __restrict__ w1lo,
                                               ushort* __restrict__ w2hi, ushort* __restrict__ w2lo,
                                               float* __restrict__ b1f, float* __restrict__ b2f,
                                               const int* __restrict__ flags) {
    int isf32 = flags[0];
    int u = blockIdx.x, t = threadIdx.x;
    if (u < 144) {
        wprep_elem(W1, al1, ar1, 256, 8, w1hi, w1lo, isf32, u * 256 + t);
    } else if (u < 216) {
        wprep_elem(W2, al2, ar2, 128, 7, w2hi, w2lo, isf32, (u - 144) * 256 + t);
    } else {
        if (t < 128) b1f[t] = ldf(b1, t, isf32);
        else b2f[t - 128] = ldf(b2, t - 128, isf32);
    }
}

// coalesced featg tile store via per-wave LDS region
__device__ __forceinline__ void store_tile(_Float16 (*sfe)[72], _Float16* featg,
                                           const f32x4* acc, int lane, int quad, int l16,
                                           int rowb0, int cbase) {
#pragma unroll
    for (int ci = 0; ci < 4; ++ci)
#pragma unroll
        for (int r = 0; r < 4; ++r)
            sfe[quad * 4 + r][ci * 16 + l16] = (_Float16)acc[ci][r];
    int rr = lane >> 3, ch = lane & 7;
#pragma unroll
    for (int s = 0; s < 2; ++s) {
        int row = s * 8 + rr;
        short8 v = *(const short8*)&sfe[row][ch * 8];
        *(short8*)(featg + (size_t)(rowb0 + row) * D1 + cbase * 16 + ch * 8) = v;
    }
}

// gemm1, 9 c-tiles per wave (A fetched ONCE into registers)
__device__ __forceinline__ void gemm1_wave9(const void* A, const ushort* Bhi, const ushort* Blo,
                                            _Float16* featg, float* el, float* er,
                                            int isf32, int rt, int lane, _Float16 (*sfe)[72]) {
    int quad = lane >> 4, l16 = lane & 15;
    const int K = 256;
    size_t a_off = (size_t)(rt * 16 + l16) * K + quad * 8;
    int rowb0 = rt * 16;

    short8 ahi[8], alo[8];
    if (isf32) {
        const float* ap = (const float*)A + a_off;
#pragma unroll
        for (int i = 0; i < 8; ++i) {
            f32x4 u0 = *(const f32x4*)(ap + 32 * i);
            f32x4 u1 = *(const f32x4*)(ap + 32 * i + 4);
            float a8[8] = {u0[0], u0[1], u0[2], u0[3], u1[0], u1[1], u1[2], u1[3]};
#pragma unroll
            for (int j = 0; j < 8; ++j) {
                ushort h, l;
                splitbf(a8[j], h, l);
                ahi[i][j] = (short)h; alo[i][j] = (short)l;
            }
        }
    } else {
        const ushort* ap = (const ushort*)A + a_off;
#pragma unroll
        for (int i = 0; i < 8; ++i) ahi[i] = *(const short8*)(ap + 32 * i);
    }

#pragma unroll
    for (int g = 0; g < 2; ++g) {
        f32x4 acc[4];
#pragma unroll
        for (int ci = 0; ci < 4; ++ci) acc[ci] = (f32x4){0.f, 0.f, 0.f, 0.f};
#pragma unroll
        for (int ci = 0; ci < 4; ++ci) {
            int c = g * 4 + ci;
            const ushort* bh = Bhi + (size_t)(c * 16 + l16) * K + quad * 8;
            if (isf32) {
                const ushort* bl = Blo + (size_t)(c * 16 + l16) * K + quad * 8;
#pragma unroll
                for (int k = 0; k < 8; ++k) {
                    short8 bh8 = *(const short8*)(bh + 32 * k);
                    short8 bl8 = *(const short8*)(bl + 32 * k);
                    acc[ci] = __builtin_amdgcn_mfma_f32_16x16x32_bf16(ahi[k], bh8, acc[ci], 0, 0, 0);
                    acc[ci] = __builtin_amdgcn_mfma_f32_16x16x32_bf16(ahi[k], bl8, acc[ci], 0, 0, 0);
                    acc[ci] = __builtin_amdgcn_mfma_f32_16x16x32_bf16(alo[k], bh8, acc[ci], 0, 0, 0);
                }
            } else {
#pragma unroll
                for (int k = 0; k < 8; ++k) {
                    short8 bh8 = *(const short8*)(bh + 32 * k);
                    acc[ci] = __builtin_amdgcn_mfma_f32_16x16x32_bf16(ahi[k], bh8, acc[ci], 0, 0, 0);
                }
            }
        }
        store_tile(sfe, featg, acc, lane, quad, l16, rowb0, g * 4);
    }

    // el/er fold tile (c=8)
    {
        const ushort* bh = Bhi + (size_t)(8 * 16 + l16) * K + quad * 8;
        const ushort* bl = Blo + (size_t)(8 * 16 + l16) * K + quad * 8;
        f32x4 a = {0.f, 0.f, 0.f, 0.f};
#pragma unroll
        for (int k = 0; k < 8; ++k) {
            short8 bh8 = *(const short8*)(bh + 32 * k);
            short8 bl8 = *(const short8*)(bl + 32 * k);
            a = __builtin_amdgcn_mfma_f32_16x16x32_bf16(ahi[k], bh8, a, 0, 0, 0);
            a = __builtin_amdgcn_mfma_f32_16x16x32_bf16(ahi[k], bl8, a, 0, 0, 0);
            if (isf32) a = __builtin_amdgcn_mfma_f32_16x16x32_bf16(alo[k], bh8, a, 0, 0, 0);
        }
#pragma unroll
        for (int r = 0; r < 4; ++r) {
            int row = rowb0 + quad * 4 + r;
            if (l16 < 8) el[row * 8 + l16] = a[r];
            else         er[row * 8 + (l16 - 8)] = a[r];
        }
    }
}

// block-level inclusive scan helper over sm[256]
__device__ __forceinline__ void block_scan(int* sm, int t) {
    for (int off = 1; off < 256; off <<= 1) {
        int v = (t >= off) ? sm[t - off] : 0;
        __syncthreads();
        sm[t] += v;
        __syncthreads();
    }
}

// LDS budget for the union kernel: bucket1 needs 28376 B, gemm1 needs 9216 B.
#define B1_SMEM 28384

// ---- phase C: bucket1 (blocks 0..319: LDS counting-sort by dst>>8, coalesced out)
//               || gemm1 (blocks 320..1101) ----
__global__ __launch_bounds__(256) void k_b1gemm1(const int4* __restrict__ src4, const int4* __restrict__ dst4,
                                                 int* __restrict__ gcur, uint* __restrict__ pkbuf,
                                                 const void* __restrict__ A,
                                                 const ushort* __restrict__ w1hi, const ushort* __restrict__ w1lo,
                                                 _Float16* __restrict__ featg,
                                                 float* __restrict__ el, float* __restrict__ er,
                                                 const int* __restrict__ flags) {
    __shared__ __align__(16) char smem[B1_SMEM];
    int b = blockIdx.x, t = threadIdx.x;
    if (b < B1BLK) {
        uint*  stage = (uint*)smem;                  // 5000 uint  = 20000
        uchar* bid   = (uchar*)(smem + 20000);       // 5000 uchar = 5000
        uint*  cnt   = (uint*)(smem + 25000);        // 196*4 = 784
        int*   loff  = (int*)(smem + 25784);         // 784
        int*   goff  = (int*)(smem + 26568);         // 784
        int*   sm    = (int*)(smem + 27352);         // 1024 -> 28376
        for (int w = t; w < NB; w += 256) cnt[w] = 0;
        __syncthreads();
        int base4 = b * (EPB1 / 4);
        // pass 1: count buckets
        for (int g = t; g < EPB1 / 4; g += 256) {
            int4 d = dst4[base4 + g];
            atomicAdd(&cnt[d.x >> 8], 1u);
            atomicAdd(&cnt[d.y >> 8], 1u);
            atomicAdd(&cnt[d.z >> 8], 1u);
            atomicAdd(&cnt[d.w >> 8], 1u);
        }
        __syncthreads();
        int c = (t < NB) ? (int)cnt[t] : 0;
        sm[t] = c;
        __syncthreads();
        block_scan(sm, t);
        if (t < NB) {
            loff[t] = sm[t] - c;                       // exclusive local offset
            goff[t] = atomicAdd(&gcur[t], c);          // reserve global space
            cnt[t] = 0;                                // reset for rank pass
        }
        __syncthreads();
        // pass 2: scatter into LDS stage sorted by bucket, record bucket id
        for (int g = t; g < EPB1 / 4; g += 256) {
            int4 s = src4[base4 + g];
            int4 d = dst4[base4 + g];
            { int bk = d.x >> 8; int r = atomicAdd(&cnt[bk], 1u); int p = loff[bk] + r; stage[p] = ((uint)s.x << 8) | (uint)(d.x & 255); bid[p] = (uchar)bk; }
            { int bk = d.y >> 8; int r = atomicAdd(&cnt[bk], 1u); int p = loff[bk] + r; stage[p] = ((uint)s.y << 8) | (uint)(d.y & 255); bid[p] = (uchar)bk; }
            { int bk = d.z >> 8; int r = atomicAdd(&cnt[bk], 1u); int p = loff[bk] + r; stage[p] = ((uint)s.z << 8) | (uint)(d.z & 255); bid[p] = (uchar)bk; }
            { int bk = d.w >> 8; int r = atomicAdd(&cnt[bk], 1u); int p = loff[bk] + r; stage[p] = ((uint)s.w << 8) | (uint)(d.w & 255); bid[p] = (uchar)bk; }
        }
        __syncthreads();
        // pass 3: one linear loop, per-element direct destination
        for (int k = t; k < EPB1; k += 256) {
            int bk = (int)bid[k];
            int gi = goff[bk] + (k - loff[bk]);
            if (gi < BCAP) pkbuf[(size_t)bk * BCAP + gi] = stage[k];
        }
    } else {
        int g = b - B1BLK;
        _Float16 (*sfe4)[16][72] = (_Float16(*)[16][72])smem;
        int wave = t >> 6, lane = t & 63;
        int rt = g * 4 + wave;
        if (rt < RTILES)
            gemm1_wave9(A, w1hi, w1lo, featg, el, er, flags[0], rt, lane, sfe4[wave]);
    }
}

// ---- phase C2: scan bucket totals -> bucket bases; rowptr[N] ----
__global__ __launch_bounds__(256) void k_bscan(const int* __restrict__ gcur, int* __restrict__ bbase,
                                               int* __restrict__ rowptr) {
    __shared__ int sm[256];
    int t = threadIdx.x;
    int x = (t < NB) ? gcur[t] : 0;
    sm[t] = x;
    __syncthreads();
    block_scan(sm, t);
    if (t == 0) bbase[0] = 0;
    bbase[t + 1] = sm[t];
    if (t == NB - 1) rowptr[N_NODES] = sm[t];
}

// ---- phase C3: per-bucket LDS scatter -> coalesced esrc + rowptr ----
__global__ __launch_bounds__(256) void k_bucket2(const uint* __restrict__ pkbuf, const int* __restrict__ gcur,
                                                 const int* __restrict__ bbase,
                                                 ushort* __restrict__ esrc, int* __restrict__ rowptr) {
    __shared__ __align__(16) char smem[76800];
    uint*   pk    = (uint*)smem;                   // 12288 uint = 49152
    ushort* es    = (ushort*)(smem + 49152);       // 12288 ushort = 24576
    uint*   ncnt  = (uint*)(smem + 73728);         // 256
    int*    nbase = (int*)(smem + 74752);          // 256
    int*    sm    = (int*)(smem + 75776);          // 256
    int b = blockIdx.x, t = threadIdx.x;
    int nb = gcur[b]; if (nb > BCAP) nb = BCAP;
    int bb0 = bbase[b];
    ncnt[t] = 0;
    __syncthreads();
    // load bucket, count per node
    for (int k = t; k < nb; k += 256) {
        uint u = pkbuf[(size_t)b * BCAP + k];
        pk[k] = u;
        atomicAdd(&ncnt[u & 255u], 1u);
    }
    __syncthreads();
    int c = (int)ncnt[t];
    sm[t] = c;
    __syncthreads();
    block_scan(sm, t);
    nbase[t] = sm[t] - c;                          // exclusive prefix within bucket
    int v = b * 256 + t;
    if (v < N_NODES) rowptr[v] = bb0 + sm[t] - c;
    ncnt[t] = 0;                                   // reset for rank pass
    __syncthreads();
    // scatter src into LDS image of the esrc segment
    for (int k = t; k < nb; k += 256) {
        uint u = pk[k];
        int n = (int)(u & 255u);
        int r = (int)atomicAdd(&ncnt[n], 1u);
        int p = nbase[n] + r;
        if (p < BCAP) es[p] = (ushort)(u >> 8);
    }
    __syncthreads();
    // stream out coalesced
    for (int k = t; k < nb; k += 256)
        esrc[bb0 + k] = es[k];
}

// ---- wide gather core v2: 64-edge chunk preload, upfront w[8], 8-slot unrolled MLP consume ----
// Lane roles: h8=lane&7/esel=lane>>3 for w(edge,head); part=lane&15 owns channels part*8..+7,
// a=lane>>4 owns edge-slots {a, a+4} of each batch.
__device__ __forceinline__ void gather_wide(const int* __restrict__ rowptr, const ushort* __restrict__ esrc,
                                            const _Float16* __restrict__ featg,
                                            const float* __restrict__ el, const float* __restrict__ er,
                                            int v, int lane, float (&acc)[8], float& den, int& deg) {
    int h8 = lane & 7, esel = lane >> 3;
    int part = lane & 15, a = lane >> 4, hpart = part >> 1;
    float erv = er[v * 8 + h8];
    int beg = rowptr[v], end = rowptr[v + 1];
    deg = end - beg;
#pragma unroll
    for (int c = 0; c < 8; ++c) acc[c] = 0.f;
    den = 0.f;
    for (int j = beg; j < end; j += 64) {
        int m = end - j; if (m > 64) m = 64;
        int idx = j + lane; if (idx >= end) idx = end - 1;
        int sv = (int)esrc[idx];                 // ONE coalesced load covers 64 edges
        int fb = (m + 7) >> 3;                   // batches incl. partial (wave-uniform)
        // upfront attention weights for all batches (independent gathers -> deep MLP)
        float w[8];
#pragma unroll
        for (int bb = 0; bb < 8; ++bb) {
            if (bb < fb) {
                int e = bb * 8 + esel;
                int se = __shfl(sv, e);
                float x = el[se * 8 + h8] + erv;
                x = x > 0.f ? x : NEG_SLOPE * x;
                w[bb] = (e < m) ? __expf(x) : 0.f;
            } else {
                w[bb] = 0.f;
            }
        }
        // featg consume: loads depend only on sv/w registers -> back-to-back row gathers
#pragma unroll
        for (int bb = 0; bb < 8; ++bb) {
            if (bb < fb) {
                int s0 = __shfl(sv, bb * 8 + a);
                int s1 = __shfl(sv, bb * 8 + a + 4);
                half8 g0 = *(const half8*)(featg + (size_t)s0 * 128 + part * 8);
                half8 g1 = *(const half8*)(featg + (size_t)s1 * 128 + part * 8);
                float w0 = __shfl(w[bb], a * 8 + hpart);
                float w1 = __shfl(w[bb], (a + 4) * 8 + hpart);
                den += w0 + w1;
#pragma unroll
                for (int c = 0; c < 8; ++c)
                    acc[c] = fmaf(w0, (float)g0[c], fmaf(w1, (float)g1[c], acc[c]));
            }
        }
    }
    // merge edge-slots (lane bits 4,5)
#pragma unroll
    for (int c = 0; c < 8; ++c) {
        acc[c] += __shfl_xor(acc[c], 16);
        acc[c] += __shfl_xor(acc[c], 32);
    }
    den += __shfl_xor(den, 16);
    den += __shfl_xor(den, 32);
}

// ---- phase D: agg layer 1 (wide gather v2) + fused MFMA dense (layer-2 transform) ----
__global__ __launch_bounds__(256) void k_agg1m(const int* __restrict__ rowptr, const ushort* __restrict__ esrc,
                                               const _Float16* __restrict__ featg,
                                               const float* __restrict__ el, const float* __restrict__ er,
                                               const float* __restrict__ b1f,
                                               const ushort* __restrict__ w2hi, const ushort* __restrict__ w2lo,
                                               _Float16* __restrict__ featg2,
                                               float* __restrict__ el2, float* __restrict__ er2,
                                               const int* __restrict__ flags) {
    __shared__ __align__(16) ushort sh_hi[16][136];
    __shared__ __align__(16) ushort sh_lo[16][136];
    int isf32 = flags[0];
    int wave = threadIdx.x >> 6, lane = threadIdx.x & 63;
    int part = lane & 15, a = lane >> 4;
    int vb = blockIdx.x * 16;
    f32x4 bia0 = *(const f32x4*)(b1f + part * 8);
    f32x4 bia1 = *(const f32x4*)(b1f + part * 8 + 4);
#pragma unroll 1
    for (int i = 0; i < 4; ++i) {
        int v = vb + wave * 4 + i;
        float acc[8], den; int dg;
        gather_wide(rowptr, esrc, featg, el, er, v, lane, acc, den, dg);
        float inv = (dg > 0) ? 1.0f / den : 0.f;
        if (a == 0) {
            short8 hi8, lo8;
#pragma unroll
            for (int c = 0; c < 8; ++c) {
                float bc = (c < 4) ? bia0[c] : bia1[c - 4];
                float r = fmaf(acc[c], inv, bc);
                r = r > 0.f ? r : (__expf(r) - 1.f);   // ELU
                ushort h, l;
                splitbf(r, h, l);
                hi8[c] = (short)h; lo8[c] = (short)l;
            }
            int m = wave * 4 + i;
            *(short8*)&sh_hi[m][part * 8] = hi8;
            *(short8*)&sh_lo[m][part * 8] = lo8;
        }
    }
    __syncthreads();

    // MFMA epilogue: y = h @ W2ext (K=128)
    int quad = lane >> 4, l16 = lane & 15;
    const int K = 128;
    short8 ahi[4], alo[4];
#pragma unroll
    for (int k = 0; k < 4; ++k) {
        ahi[k] = *(const short8*)&sh_hi[l16][quad * 8 + 32 * k];
        alo[k] = *(const short8*)&sh_lo[l16][quad * 8 + 32 * k];
    }
    int ntile = (wave == 0) ? 3 : 2;
    for (int ti = 0; ti < ntile; ++ti) {
        int c = (ti == 2) ? 8 : wave + ti * 4;
        const ushort* bh = w2hi + (size_t)(c * 16 + l16) * K + quad * 8;
        const ushort* bl = w2lo + (size_t)(c * 16 + l16) * K + quad * 8;
        f32x4 aa = {0.f, 0.f, 0.f, 0.f};
#pragma unroll
        for (int k = 0; k < 4; ++k) {
            short8 bh8 = *(const short8*)(bh + 32 * k);
            aa = __builtin_amdgcn_mfma_f32_16x16x32_bf16(ahi[k], bh8, aa, 0, 0, 0);
            aa = __builtin_amdgcn_mfma_f32_16x16x32_bf16(alo[k], bh8, aa, 0, 0, 0);
            if (c == 8 || isf32) {
                short8 bl8 = *(const short8*)(bl + 32 * k);
                aa = __builtin_amdgcn_mfma_f32_16x16x32_bf16(ahi[k], bl8, aa, 0, 0, 0);
            }
        }
        if (c < 8) {
#pragma unroll
            for (int r = 0; r < 4; ++r)
                featg2[(size_t)(vb + quad * 4 + r) * D1 + c * 16 + l16] = (_Float16)aa[r];
        } else {
#pragma unroll
            for (int r = 0; r < 4; ++r) {
                int row = vb + quad * 4 + r;
                if (l16 < 8) el2[row * 8 + l16] = aa[r];
                else         er2[row * 8 + (l16 - 8)] = aa[r];
            }
        }
    }
}

// ---- phase E: agg layer 2 (wide gather v2) -> head-mean -> d_out ----
__global__ __launch_bounds__(256) void k_agg2(const int* __restrict__ rowptr, const ushort* __restrict__ esrc,
                                              const _Float16* __restrict__ featg2,
                                              const float* __restrict__ el2, const float* __restrict__ er2,
                                              const float* __restrict__ b2f,
                                              void* __restrict__ out, const int* __restrict__ flags) {
    int wave = threadIdx.x >> 6, lane = threadIdx.x & 63;
    int v = blockIdx.x * 4 + wave;
    if (v >= N_NODES) return;
    int part = lane & 15;
    float acc[8], den; int dg;
    gather_wide(rowptr, esrc, featg2, el2, er2, v, lane, acc, den, dg);
    float inv = (dg > 0) ? 1.0f / den : 0.f;
    f32x4 bia0 = *(const f32x4*)(b2f + part * 8);
    f32x4 bia1 = *(const f32x4*)(b2f + part * 8 + 4);
    float r[8];
#pragma unroll
    for (int c = 0; c < 8; ++c) {
        float bc = (c < 4) ? bia0[c] : bia1[c - 4];
        r[c] = fmaf(acc[c], inv, bc);
    }
    // head-mean: sum over part bits 1..3 (head index)
#pragma unroll
    for (int c = 0; c < 8; ++c) {
        r[c] += __shfl_xor(r[c], 2);
        r[c] += __shfl_xor(r[c], 4);
        r[c] += __shfl_xor(r[c], 8);
        r[c] *= 0.125f;
    }
    if (lane < 2) {
        if (flags[0]) {
            float* op = (float*)out + (size_t)v * 16 + lane * 8;
            f32x4 o0 = {r[0], r[1], r[2], r[3]};
            f32x4 o1 = {r[4], r[5], r[6], r[7]};
            *(f32x4*)op = o0;
            *(f32x4*)(op + 4) = o1;
        } else {
            short8 pk;
#pragma unroll
            for (int c = 0; c < 8; ++c) pk[c] = (short)f2bf(r[c]);
            *(short8*)((ushort*)out + (size_t)v * 16 + lane * 8) = pk;
        }
    }
}

extern "C" void kernel_launch(void* const* d_in, const int* in_sizes, int n_in,
                              void* d_out, int out_size, void* d_ws, size_t ws_size,
                              hipStream_t stream) {
    const void* node_feat = d_in[0];
    const int4* src4 = (const int4*)d_in[1];
    const int4* dst4 = (const int4*)d_in[2];
    const void* W1 = d_in[3];
    const void* al1 = d_in[4];
    const void* ar1 = d_in[5];
    const void* b1 = d_in[6];
    const void* W2 = d_in[7];
    const void* al2 = d_in[8];
    const void* ar2 = d_in[9];
    const void* b2 = d_in[10];
    char* ws = (char*)d_ws;

    int* rowptr = (int*)(ws + O_ROWPTR);
    int* gcur   = (int*)(ws + O_GCUR);
    int* bbase  = (int*)(ws + O_BBASE);
    int* flags  = (int*)(ws + O_FLAGS);
    ushort* esrc = (ushort*)(ws + O_ESRC);
    uint* pkbuf = (uint*)(ws + O_PKBUF);
    ushort* w1hi = (ushort*)(ws + O_W1HI);
    ushort* w1lo = (ushort*)(ws + O_W1LO);
    ushort* w2hi = (ushort*)(ws + O_W2HI);
    ushort* w2lo = (ushort*)(ws + O_W2LO);
    float* b1f  = (float*)(ws + O_B1F);
    float* b2f  = (float*)(ws + O_B2F);
    _Float16* featg = (_Float16*)(ws + O_FEATG);
    float* el   = (float*)(ws + O_EL);
    float* er   = (float*)(ws + O_ER);
    _Float16* featg2 = (_Float16*)(ws + O_FEATG2);
    float* el2  = (float*)(ws + O_EL2);
    float* er2  = (float*)(ws + O_ER2);

    // A: dtype detect + zero bucket cursors
    k_detect<<<2, 256, 0, stream>>>((const ushort*)W1, flags, gcur);
    // B: weight prep
    k_wprep<<<217, 256, 0, stream>>>(W1, al1, ar1, b1, W2, al2, ar2, b2,
                                     w1hi, w1lo, w2hi, w2lo, b1f, b2f, flags);
    // C: bucket1 (LDS counting-sort, coalesced out) || gemm1
    k_b1gemm1<<<B1BLK + 782, 256, 0, stream>>>(src4, dst4, gcur, pkbuf,
                                               node_feat, w1hi, w1lo, featg, el, er, flags);
    // C2: bucket bases
    k_bscan<<<1, 256, 0, stream>>>(gcur, bbase, rowptr);
    // C3: per-bucket LDS scatter -> esrc + rowptr
    k_bucket2<<<NB, 256, 0, stream>>>(pkbuf, gcur, bbase, esrc, rowptr);
    // D: agg layer 1 (wide v2) + fused MFMA dense
    k_agg1m<<<N_NODES / 16, 256, 0, stream>>>(rowptr, esrc, featg, el, er, b1f,
                                              w2hi, w2lo, featg2, el2, er2, flags);
    // E: agg layer 2 (wide v2) -> output
    k_agg2<<<(N_NODES + 3) / 4, 256, 0, stream>>>(rowptr, esrc, featg2, el2, er2,
                                                  b2f, d_out, flags);
}

// Round 7
// 371.657 us; speedup vs baseline: 1.0523x; 1.0523x over previous
//
#include <hip/hip_runtime.h>
#include <hip/hip_bf16.h>

#define N_NODES 50000
#define N_EDGES 1600000
#define HEADS 8
#define HDIM 16
#define D1 128   // HEADS*HDIM
#define NEG_SLOPE 0.2f
#define RTILES 3125    // 50000/16
#define NB 196         // dst buckets (dst>>8), 49999>>8 = 195
#define BCAP 12288     // per-bucket capacity (avg fill 8163 -> huge margin)
#define B1BLK 320      // bucket1 blocks
#define EPB1 5000      // edges per bucket1 block (320*5000 = 1.6M)
#define WPREP_BLKS 217 // wprep blocks inside k_wb1

typedef short short8 __attribute__((ext_vector_type(8)));
typedef float f32x4 __attribute__((ext_vector_type(4)));
typedef _Float16 half8 __attribute__((ext_vector_type(8)));
typedef unsigned char uchar;

// ---- dtype helpers (isf32: 1 = buffers are fp32, 0 = bf16) ----
__device__ __forceinline__ float bf2f(ushort u) {
    union { unsigned u; float f; } x; x.u = ((unsigned)u) << 16; return x.f;
}
__device__ __forceinline__ ushort f2bf(float f) {
    union { float f; unsigned u; } x; x.f = f;
    unsigned r = x.u + 0x7FFF + ((x.u >> 16) & 1);   // RNE
    return (ushort)(r >> 16);
}
__device__ __forceinline__ float ldf(const void* p, size_t i, int isf32) {
    return isf32 ? ((const float*)p)[i] : bf2f(((const ushort*)p)[i]);
}
__device__ __forceinline__ void splitbf(float f, ushort& hi, ushort& lo) {
    unsigned u = __float_as_uint(f);
    unsigned uh = u & 0xFFFF0000u;
    hi = (ushort)(uh >> 16);
    lo = f2bf(f - __uint_as_float(uh));
}

// ---------------- workspace layout (bytes) ----------------
#define O_ROWPTR   0            // int[50001]
#define O_GCUR     200064       // int[196] per-bucket cursors
#define O_FLAGS    602240
#define O_ESRC     2202624      // ushort[1600000] CSR edge srcs
#define O_W1HI     5402624      // 144x256 bf16
#define O_W1LO     5476352
#define O_W2HI     5550080      // 144x128 bf16
#define O_W2LO     5586944
#define O_B1F      5623808
#define O_B2F      5624320
#define O_FEATG    5624832      // fp16 [N][128] layer-1 features
#define O_EL       18424832
#define O_ER       20024832
#define O_FEATG2   21624832     // fp16 [N][128] layer-2 features
#define O_EL2      34424832
#define O_ER2      36024832
// end: 37624832 (37.6 MB)
// alias inside O_FEATG2 (12.8 MB), dead before agg1m writes featg2:
#define O_PKBUF    O_FEATG2     // uint[196][12288] = 9.63 MB packed bucketed edges

// ================= device helpers =================

// ---- phase A: dtype detect (block 0) + zero bucket cursors (block 1) ----
__global__ __launch_bounds__(256) void k_detect(const ushort* __restrict__ w1, int* __restrict__ flags,
                                                int* __restrict__ gcur) {
    __shared__ int sm[256];
    int t = threadIdx.x;
    if (blockIdx.x == 1) {
        if (t < NB) gcur[t] = 0;
        return;
    }
    int cnt = 0;
    for (int i = t; i < 32768; i += 256) {
        int e = (w1[i] >> 7) & 0xFF;
        if (e >= 0xC8) cnt++;
    }
    sm[t] = cnt; __syncthreads();
    for (int off = 128; off > 0; off >>= 1) {
        if (t < off) sm[t] += sm[t + off];
        __syncthreads();
    }
    if (t == 0) flags[0] = (sm[0] > 0) ? 1 : 0;
}

// W -> whi/wlo bf16 [144][K] transposed (rows 0..127 = W cols, 128..135 = W@al, 136..143 = W@ar)
__device__ __forceinline__ void wprep_elem(const void* W, const void* al, const void* ar,
                                           int K, int kshift, ushort* whi, ushort* wlo,
                                           int isf32, int idx) {
    if (idx >= 144 * K) return;
    int n = idx >> kshift, k = idx & (K - 1);
    float f;
    if (n < 128) {
        f = ldf(W, (size_t)k * 128 + n, isf32);
    } else if (n < 136) {
        int h = n - 128;
        f = 0.f;
#pragma unroll
        for (int d = 0; d < HDIM; ++d)
            f = fmaf(ldf(W, (size_t)k * 128 + h * 16 + d, isf32), ldf(al, h * 16 + d, isf32), f);
    } else {
        int h = n - 136;
        f = 0.f;
#pragma unroll
        for (int d = 0; d < HDIM; ++d)
            f = fmaf(ldf(W, (size_t)k * 128 + h * 16 + d, isf32), ldf(ar, h * 16 + d, isf32), f);
    }
    ushort hi = f2bf(f);
    wlo[n * K + k] = f2bf(f - bf2f(hi));
    whi[n * K + k] = hi;
}

// block-level inclusive scan helper over sm[256]
__device__ __forceinline__ void block_scan(int* sm, int t) {
    for (int off = 1; off < 256; off <<= 1) {
        int v = (t >= off) ? sm[t - off] : 0;
        __syncthreads();
        sm[t] += v;
        __syncthreads();
    }
}

// LDS budget for the wprep||bucket1 union kernel: bucket1 needs 28376 B.
#define B1_SMEM 28384

// ---- phase B: wprep (blocks 0..216) || bucket1 (blocks 217..536) ----
// Both depend only on k_detect (flags / gcur). wprep is LDS-free so the union LDS is harmless.
__global__ __launch_bounds__(256) void k_wb1(const void* __restrict__ W1, const void* __restrict__ al1,
                                             const void* __restrict__ ar1, const void* __restrict__ b1,
                                             const void* __restrict__ W2, const void* __restrict__ al2,
                                             const void* __restrict__ ar2, const void* __restrict__ b2,
                                             ushort* __restrict__ w1hi, ushort* __restrict__ w1lo,
                                             ushort* __restrict__ w2hi, ushort* __restrict__ w2lo,
                                             float* __restrict__ b1f, float* __restrict__ b2f,
                                             const int4* __restrict__ src4, const int4* __restrict__ dst4,
                                             int* __restrict__ gcur, uint* __restrict__ pkbuf,
                                             const int* __restrict__ flags) {
    __shared__ __align__(16) char smem[B1_SMEM];
    int b = blockIdx.x, t = threadIdx.x;
    if (b < WPREP_BLKS) {
        int isf32 = flags[0];
        if (b < 144) {
            wprep_elem(W1, al1, ar1, 256, 8, w1hi, w1lo, isf32, b * 256 + t);
        } else if (b < 216) {
            wprep_elem(W2, al2, ar2, 128, 7, w2hi, w2lo, isf32, (b - 144) * 256 + t);
        } else {
            if (t < 128) b1f[t] = ldf(b1, t, isf32);
            else b2f[t - 128] = ldf(b2, t - 128, isf32);
        }
    } else {
        uint*  stage = (uint*)smem;                  // 5000 uint  = 20000
        uchar* bid   = (uchar*)(smem + 20000);       // 5000 uchar = 5000
        uint*  cnt   = (uint*)(smem + 25000);        // 784
        int*   loff  = (int*)(smem + 25784);         // 784
        int*   goff  = (int*)(smem + 26568);         // 784
        int*   sm    = (int*)(smem + 27352);         // 1024 -> 28376
        int bb = b - WPREP_BLKS;
        for (int w = t; w < NB; w += 256) cnt[w] = 0;
        __syncthreads();
        int base4 = bb * (EPB1 / 4);
        // pass 1: count buckets
        for (int g = t; g < EPB1 / 4; g += 256) {
            int4 d = dst4[base4 + g];
            atomicAdd(&cnt[d.x >> 8], 1u);
            atomicAdd(&cnt[d.y >> 8], 1u);
            atomicAdd(&cnt[d.z >> 8], 1u);
            atomicAdd(&cnt[d.w >> 8], 1u);
        }
        __syncthreads();
        int c = (t < NB) ? (int)cnt[t] : 0;
        sm[t] = c;
        __syncthreads();
        block_scan(sm, t);
        if (t < NB) {
            loff[t] = sm[t] - c;                       // exclusive local offset
            goff[t] = atomicAdd(&gcur[t], c);          // reserve global space
            cnt[t] = 0;                                // reset for rank pass
        }
        __syncthreads();
        // pass 2: scatter into LDS stage sorted by bucket, record bucket id
        for (int g = t; g < EPB1 / 4; g += 256) {
            int4 s = src4[base4 + g];
            int4 d = dst4[base4 + g];
            { int bk = d.x >> 8; int r = atomicAdd(&cnt[bk], 1u); int p = loff[bk] + r; stage[p] = ((uint)s.x << 8) | (uint)(d.x & 255); bid[p] = (uchar)bk; }
            { int bk = d.y >> 8; int r = atomicAdd(&cnt[bk], 1u); int p = loff[bk] + r; stage[p] = ((uint)s.y << 8) | (uint)(d.y & 255); bid[p] = (uchar)bk; }
            { int bk = d.z >> 8; int r = atomicAdd(&cnt[bk], 1u); int p = loff[bk] + r; stage[p] = ((uint)s.z << 8) | (uint)(d.z & 255); bid[p] = (uchar)bk; }
            { int bk = d.w >> 8; int r = atomicAdd(&cnt[bk], 1u); int p = loff[bk] + r; stage[p] = ((uint)s.w << 8) | (uint)(d.w & 255); bid[p] = (uchar)bk; }
        }
        __syncthreads();
        // pass 3: one linear loop, per-element direct destination
        for (int k = t; k < EPB1; k += 256) {
            int bk = (int)bid[k];
            int gi = goff[bk] + (k - loff[bk]);
            if (gi < BCAP) pkbuf[(size_t)bk * BCAP + gi] = stage[k];
        }
    }
}

// coalesced featg tile store via per-wave LDS region
__device__ __forceinline__ void store_tile(_Float16 (*sfe)[72], _Float16* featg,
                                           const f32x4* acc, int lane, int quad, int l16,
                                           int rowb0, int cbase) {
#pragma unroll
    for (int ci = 0; ci < 4; ++ci)
#pragma unroll
        for (int r = 0; r < 4; ++r)
            sfe[quad * 4 + r][ci * 16 + l16] = (_Float16)acc[ci][r];
    int rr = lane >> 3, ch = lane & 7;
#pragma unroll
    for (int s = 0; s < 2; ++s) {
        int row = s * 8 + rr;
        short8 v = *(const short8*)&sfe[row][ch * 8];
        *(short8*)(featg + (size_t)(rowb0 + row) * D1 + cbase * 16 + ch * 8) = v;
    }
}

// gemm1, 9 c-tiles per wave (A fetched ONCE into registers)
__device__ __forceinline__ void gemm1_wave9(const void* A, const ushort* Bhi, const ushort* Blo,
                                            _Float16* featg, float* el, float* er,
                                            int isf32, int rt, int lane, _Float16 (*sfe)[72]) {
    int quad = lane >> 4, l16 = lane & 15;
    const int K = 256;
    size_t a_off = (size_t)(rt * 16 + l16) * K + quad * 8;
    int rowb0 = rt * 16;

    short8 ahi[8], alo[8];
    if (isf32) {
        const float* ap = (const float*)A + a_off;
#pragma unroll
        for (int i = 0; i < 8; ++i) {
            f32x4 u0 = *(const f32x4*)(ap + 32 * i);
            f32x4 u1 = *(const f32x4*)(ap + 32 * i + 4);
            float a8[8] = {u0[0], u0[1], u0[2], u0[3], u1[0], u1[1], u1[2], u1[3]};
#pragma unroll
            for (int j = 0; j < 8; ++j) {
                ushort h, l;
                splitbf(a8[j], h, l);
                ahi[i][j] = (short)h; alo[i][j] = (short)l;
            }
        }
    } else {
        const ushort* ap = (const ushort*)A + a_off;
#pragma unroll
        for (int i = 0; i < 8; ++i) ahi[i] = *(const short8*)(ap + 32 * i);
    }

#pragma unroll
    for (int g = 0; g < 2; ++g) {
        f32x4 acc[4];
#pragma unroll
        for (int ci = 0; ci < 4; ++ci) acc[ci] = (f32x4){0.f, 0.f, 0.f, 0.f};
#pragma unroll
        for (int ci = 0; ci < 4; ++ci) {
            int c = g * 4 + ci;
            const ushort* bh = Bhi + (size_t)(c * 16 + l16) * K + quad * 8;
            if (isf32) {
                const ushort* bl = Blo + (size_t)(c * 16 + l16) * K + quad * 8;
#pragma unroll
                for (int k = 0; k < 8; ++k) {
                    short8 bh8 = *(const short8*)(bh + 32 * k);
                    short8 bl8 = *(const short8*)(bl + 32 * k);
                    acc[ci] = __builtin_amdgcn_mfma_f32_16x16x32_bf16(ahi[k], bh8, acc[ci], 0, 0, 0);
                    acc[ci] = __builtin_amdgcn_mfma_f32_16x16x32_bf16(ahi[k], bl8, acc[ci], 0, 0, 0);
                    acc[ci] = __builtin_amdgcn_mfma_f32_16x16x32_bf16(alo[k], bh8, acc[ci], 0, 0, 0);
                }
            } else {
#pragma unroll
                for (int k = 0; k < 8; ++k) {
                    short8 bh8 = *(const short8*)(bh + 32 * k);
                    acc[ci] = __builtin_amdgcn_mfma_f32_16x16x32_bf16(ahi[k], bh8, acc[ci], 0, 0, 0);
                }
            }
        }
        store_tile(sfe, featg, acc, lane, quad, l16, rowb0, g * 4);
    }

    // el/er fold tile (c=8)
    {
        const ushort* bh = Bhi + (size_t)(8 * 16 + l16) * K + quad * 8;
        const ushort* bl = Blo + (size_t)(8 * 16 + l16) * K + quad * 8;
        f32x4 a = {0.f, 0.f, 0.f, 0.f};
#pragma unroll
        for (int k = 0; k < 8; ++k) {
            short8 bh8 = *(const short8*)(bh + 32 * k);
            short8 bl8 = *(const short8*)(bl + 32 * k);
            a = __builtin_amdgcn_mfma_f32_16x16x32_bf16(ahi[k], bh8, a, 0, 0, 0);
            a = __builtin_amdgcn_mfma_f32_16x16x32_bf16(ahi[k], bl8, a, 0, 0, 0);
            if (isf32) a = __builtin_amdgcn_mfma_f32_16x16x32_bf16(alo[k], bh8, a, 0, 0, 0);
        }
#pragma unroll
        for (int r = 0; r < 4; ++r) {
            int row = rowb0 + quad * 4 + r;
            if (l16 < 8) el[row * 8 + l16] = a[r];
            else         er[row * 8 + (l16 - 8)] = a[r];
        }
    }
}

// ---- phase C: gemm1 standalone (high occupancy, 9.2 KB LDS) ----
__global__ __launch_bounds__(256) void k_gemm1(const void* __restrict__ A,
                                               const ushort* __restrict__ w1hi, const ushort* __restrict__ w1lo,
                                               _Float16* __restrict__ featg,
                                               float* __restrict__ el, float* __restrict__ er,
                                               const int* __restrict__ flags) {
    __shared__ __align__(16) _Float16 sfe[4][16][72];
    int wave = threadIdx.x >> 6, lane = threadIdx.x & 63;
    int rt = blockIdx.x * 4 + wave;
    if (rt < RTILES)
        gemm1_wave9(A, w1hi, w1lo, featg, el, er, flags[0], rt, lane, sfe[wave]);
}

// ---- phase D: per-bucket LDS scatter -> coalesced esrc + rowptr (bscan folded in) ----
__global__ __launch_bounds__(256) void k_bucket2(const uint* __restrict__ pkbuf, const int* __restrict__ gcur,
                                                 ushort* __restrict__ esrc, int* __restrict__ rowptr) {
    __shared__ __align__(16) char smem[76800];
    uint*   pk    = (uint*)smem;                   // 12288 uint = 49152
    ushort* es    = (ushort*)(smem + 49152);       // 12288 ushort = 24576
    uint*   ncnt  = (uint*)(smem + 73728);         // 256
    int*    nbase = (int*)(smem + 74752);          // 256
    int*    sm    = (int*)(smem + 75776);          // 256
    int b = blockIdx.x, t = threadIdx.x;
    // fold bscan: scan gcur to get this bucket's base
    int x = (t < NB) ? gcur[t] : 0;
    sm[t] = x;
    __syncthreads();
    block_scan(sm, t);
    int nb = gcur[b]; if (nb > BCAP) nb = BCAP;
    int bb0 = sm[b] - gcur[b];
    if (b == 0 && t == NB - 1) rowptr[N_NODES] = sm[t];
    __syncthreads();
    ncnt[t] = 0;
    __syncthreads();
    // load bucket, count per node
    for (int k = t; k < nb; k += 256) {
        uint u = pkbuf[(size_t)b * BCAP + k];
        pk[k] = u;
        atomicAdd(&ncnt[u & 255u], 1u);
    }
    __syncthreads();
    int c = (int)ncnt[t];
    sm[t] = c;
    __syncthreads();
    block_scan(sm, t);
    nbase[t] = sm[t] - c;                          // exclusive prefix within bucket
    int v = b * 256 + t;
    if (v < N_NODES) rowptr[v] = bb0 + sm[t] - c;
    ncnt[t] = 0;                                   // reset for rank pass
    __syncthreads();
    // scatter src into LDS image of the esrc segment
    for (int k = t; k < nb; k += 256) {
        uint u = pk[k];
        int n = (int)(u & 255u);
        int r = (int)atomicAdd(&ncnt[n], 1u);
        int p = nbase[n] + r;
        if (p < BCAP) es[p] = (ushort)(u >> 8);
    }
    __syncthreads();
    // stream out coalesced
    for (int k = t; k < nb; k += 256)
        esrc[bb0 + k] = es[k];
}

// ---- wide gather core (round-5 v1, measured 93.6us): per 8-edge batch, 2x half8 row-gathers ----
// Lane roles: h8=lane&7/esel=lane>>3 compute w(edge=esel, head=h8);
// part=lane&15 owns channels part*8..+7 (head part>>1); a=lane>>4 owns edges {a, a+4}.
__device__ __forceinline__ void gather_wide(const int* __restrict__ rowptr, const ushort* __restrict__ esrc,
                                            const _Float16* __restrict__ featg,
                                            const float* __restrict__ el, const float* __restrict__ er,
                                            int v, int lane, float (&acc)[8], float& den, int& deg) {
    int h8 = lane & 7, esel = lane >> 3;
    int part = lane & 15, a = lane >> 4, hpart = part >> 1;
    float erv = er[v * 8 + h8];
    int beg = rowptr[v], end = rowptr[v + 1];
    deg = end - beg;
#pragma unroll
    for (int c = 0; c < 8; ++c) acc[c] = 0.f;
    den = 0.f;
    for (int j = beg; j < end; j += 8) {
        int nv = end - j;                       // edges valid this batch (>=1)
        int idx = j + h8; if (idx >= end) idx = end - 1;
        int sv = (int)esrc[idx];
        int se = __shfl(sv, esel);
        float x = el[se * 8 + h8] + erv;
        x = x > 0.f ? x : NEG_SLOPE * x;
        float w = __expf(x);
        if (esel >= nv) w = 0.f;                // invalid edges contribute nothing
        int s0 = __shfl(sv, a);
        int s1 = __shfl(sv, a + 4);
        half8 g0 = *(const half8*)(featg + (size_t)s0 * 128 + part * 8);
        half8 g1 = *(const half8*)(featg + (size_t)s1 * 128 + part * 8);
        float w0 = __shfl(w, a * 8 + hpart);
        float w1 = __shfl(w, (a + 4) * 8 + hpart);
        den += w0 + w1;
#pragma unroll
        for (int c = 0; c < 8; ++c)
            acc[c] = fmaf(w0, (float)g0[c], fmaf(w1, (float)g1[c], acc[c]));
    }
    // merge edge-slots (lane bits 4,5)
#pragma unroll
    for (int c = 0; c < 8; ++c) {
        acc[c] += __shfl_xor(acc[c], 16);
        acc[c] += __shfl_xor(acc[c], 32);
    }
    den += __shfl_xor(den, 16);
    den += __shfl_xor(den, 32);
}

// ---- phase E: agg layer 1 (wide gather) + fused MFMA dense (layer-2 transform) ----
__global__ __launch_bounds__(256) void k_agg1m(const int* __restrict__ rowptr, const ushort* __restrict__ esrc,
                                               const _Float16* __restrict__ featg,
                                               const float* __restrict__ el, const float* __restrict__ er,
                                               const float* __restrict__ b1f,
                                               const ushort* __restrict__ w2hi, const ushort* __restrict__ w2lo,
                                               _Float16* __restrict__ featg2,
                                               float* __restrict__ el2, float* __restrict__ er2,
                                               const int* __restrict__ flags) {
    __shared__ __align__(16) ushort sh_hi[16][136];
    __shared__ __align__(16) ushort sh_lo[16][136];
    int isf32 = flags[0];
    int wave = threadIdx.x >> 6, lane = threadIdx.x & 63;
    int part = lane & 15, a = lane >> 4;
    int vb = blockIdx.x * 16;
    f32x4 bia0 = *(const f32x4*)(b1f + part * 8);
    f32x4 bia1 = *(const f32x4*)(b1f + part * 8 + 4);
#pragma unroll
    for (int i = 0; i < 4; ++i) {
        int v = vb + wave * 4 + i;
        float acc[8], den; int dg;
        gather_wide(rowptr, esrc, featg, el, er, v, lane, acc, den, dg);
        float inv = (dg > 0) ? 1.0f / den : 0.f;
        if (a == 0) {
            short8 hi8, lo8;
#pragma unroll
            for (int c = 0; c < 8; ++c) {
                float bc = (c < 4) ? bia0[c] : bia1[c - 4];
                float r = fmaf(acc[c], inv, bc);
                r = r > 0.f ? r : (__expf(r) - 1.f);   // ELU
                ushort h, l;
                splitbf(r, h, l);
                hi8[c] = (short)h; lo8[c] = (short)l;
            }
            int m = wave * 4 + i;
            *(short8*)&sh_hi[m][part * 8] = hi8;
            *(short8*)&sh_lo[m][part * 8] = lo8;
        }
    }
    __syncthreads();

    // MFMA epilogue: y = h @ W2ext (K=128)
    int quad = lane >> 4, l16 = lane & 15;
    const int K = 128;
    short8 ahi[4], alo[4];
#pragma unroll
    for (int k = 0; k < 4; ++k) {
        ahi[k] = *(const short8*)&sh_hi[l16][quad * 8 + 32 * k];
        alo[k] = *(const short8*)&sh_lo[l16][quad * 8 + 32 * k];
    }
    int ntile = (wave == 0) ? 3 : 2;
    for (int ti = 0; ti < ntile; ++ti) {
        int c = (ti == 2) ? 8 : wave + ti * 4;
        const ushort* bh = w2hi + (size_t)(c * 16 + l16) * K + quad * 8;
        const ushort* bl = w2lo + (size_t)(c * 16 + l16) * K + quad * 8;
        f32x4 aa = {0.f, 0.f, 0.f, 0.f};
#pragma unroll
        for (int k = 0; k < 4; ++k) {
            short8 bh8 = *(const short8*)(bh + 32 * k);
            aa = __builtin_amdgcn_mfma_f32_16x16x32_bf16(ahi[k], bh8, aa, 0, 0, 0);
            aa = __builtin_amdgcn_mfma_f32_16x16x32_bf16(alo[k], bh8, aa, 0, 0, 0);
            if (c == 8 || isf32) {
                short8 bl8 = *(const short8*)(bl + 32 * k);
                aa = __builtin_amdgcn_mfma_f32_16x16x32_bf16(ahi[k], bl8, aa, 0, 0, 0);
            }
        }
        if (c < 8) {
#pragma unroll
            for (int r = 0; r < 4; ++r)
                featg2[(size_t)(vb + quad * 4 + r) * D1 + c * 16 + l16] = (_Float16)aa[r];
        } else {
#pragma unroll
            for (int r = 0; r < 4; ++r) {
                int row = vb + quad * 4 + r;
                if (l16 < 8) el2[row * 8 + l16] = aa[r];
                else         er2[row * 8 + (l16 - 8)] = aa[r];
            }
        }
    }
}

// ---- phase F: agg layer 2 (wide gather) -> head-mean -> d_out ----
__global__ __launch_bounds__(256) void k_agg2(const int* __restrict__ rowptr, const ushort* __restrict__ esrc,
                                              const _Float16* __restrict__ featg2,
                                              const float* __restrict__ el2, const float* __restrict__ er2,
                                              const float* __restrict__ b2f,
                                              void* __restrict__ out, const int* __restrict__ flags) {
    int wave = threadIdx.x >> 6, lane = threadIdx.x & 63;
    int v = blockIdx.x * 4 + wave;
    if (v >= N_NODES) return;
    int part = lane & 15;
    float acc[8], den; int dg;
    gather_wide(rowptr, esrc, featg2, el2, er2, v, lane, acc, den, dg);
    float inv = (dg > 0) ? 1.0f / den : 0.f;
    f32x4 bia0 = *(const f32x4*)(b2f + part * 8);
    f32x4 bia1 = *(const f32x4*)(b2f + part * 8 + 4);
    float r[8];
#pragma unroll
    for (int c = 0; c < 8; ++c) {
        float bc = (c < 4) ? bia0[c] : bia1[c - 4];
        r[c] = fmaf(acc[c], inv, bc);
    }
    // head-mean: sum over part bits 1..3 (head index)
#pragma unroll
    for (int c = 0; c < 8; ++c) {
        r[c] += __shfl_xor(r[c], 2);
        r[c] += __shfl_xor(r[c], 4);
        r[c] += __shfl_xor(r[c], 8);
        r[c] *= 0.125f;
    }
    if (lane < 2) {
        if (flags[0]) {
            float* op = (float*)out + (size_t)v * 16 + lane * 8;
            f32x4 o0 = {r[0], r[1], r[2], r[3]};
            f32x4 o1 = {r[4], r[5], r[6], r[7]};
            *(f32x4*)op = o0;
            *(f32x4*)(op + 4) = o1;
        } else {
            short8 pk;
#pragma unroll
            for (int c = 0; c < 8; ++c) pk[c] = (short)f2bf(r[c]);
            *(short8*)((ushort*)out + (size_t)v * 16 + lane * 8) = pk;
        }
    }
}

extern "C" void kernel_launch(void* const* d_in, const int* in_sizes, int n_in,
                              void* d_out, int out_size, void* d_ws, size_t ws_size,
                              hipStream_t stream) {
    const void* node_feat = d_in[0];
    const int4* src4 = (const int4*)d_in[1];
    const int4* dst4 = (const int4*)d_in[2];
    const void* W1 = d_in[3];
    const void* al1 = d_in[4];
    const void* ar1 = d_in[5];
    const void* b1 = d_in[6];
    const void* W2 = d_in[7];
    const void* al2 = d_in[8];
    const void* ar2 = d_in[9];
    const void* b2 = d_in[10];
    char* ws = (char*)d_ws;

    int* rowptr = (int*)(ws + O_ROWPTR);
    int* gcur   = (int*)(ws + O_GCUR);
    int* flags  = (int*)(ws + O_FLAGS);
    ushort* esrc = (ushort*)(ws + O_ESRC);
    uint* pkbuf = (uint*)(ws + O_PKBUF);
    ushort* w1hi = (ushort*)(ws + O_W1HI);
    ushort* w1lo = (ushort*)(ws + O_W1LO);
    ushort* w2hi = (ushort*)(ws + O_W2HI);
    ushort* w2lo = (ushort*)(ws + O_W2LO);
    float* b1f  = (float*)(ws + O_B1F);
    float* b2f  = (float*)(ws + O_B2F);
    _Float16* featg = (_Float16*)(ws + O_FEATG);
    float* el   = (float*)(ws + O_EL);
    float* er   = (float*)(ws + O_ER);
    _Float16* featg2 = (_Float16*)(ws + O_FEATG2);
    float* el2  = (float*)(ws + O_EL2);
    float* er2  = (float*)(ws + O_ER2);

    // A: dtype detect + zero bucket cursors
    k_detect<<<2, 256, 0, stream>>>((const ushort*)W1, flags, gcur);
    // B: wprep || bucket1 (both depend only on detect)
    k_wb1<<<WPREP_BLKS + B1BLK, 256, 0, stream>>>(W1, al1, ar1, b1, W2, al2, ar2, b2,
                                                  w1hi, w1lo, w2hi, w2lo, b1f, b2f,
                                                  src4, dst4, gcur, pkbuf, flags);
    // C: gemm1 standalone
    k_gemm1<<<782, 256, 0, stream>>>(node_feat, w1hi, w1lo, featg, el, er, flags);
    // D: bucket2 (bscan folded) -> esrc + rowptr
    k_bucket2<<<NB, 256, 0, stream>>>(pkbuf, gcur, esrc, rowptr);
    // E: agg layer 1 (wide v1) + fused MFMA dense
    k_agg1m<<<N_NODES / 16, 256, 0, stream>>>(rowptr, esrc, featg, el, er, b1f,
                                              w2hi, w2lo, featg2, el2, er2, flags);
    // F: agg layer 2 (wide v1) -> output
    k_agg2<<<(N_NODES + 3) / 4, 256, 0, stream>>>(rowptr, esrc, featg2, el2, er2,
                                                  b2f, d_out, flags);
}

// Round 9
// 351.348 us; speedup vs baseline: 1.1131x; 1.0578x over previous
//
#include <hip/hip_runtime.h>
#include <hip/hip_bf16.h>

#define N_NODES 50000
#define N_EDGES 1600000
#define HEADS 8
#define HDIM 16
#define D1 128   // HEADS*HDIM
#define NEG_SLOPE 0.2f
#define RTILES 3125    // 50000/16
#define NB 196         // dst buckets (dst>>8), 49999>>8 = 195
#define BCAP 12288     // per-bucket capacity (avg fill 8163 -> huge margin)
#define B1BLK 320      // bucket1 blocks
#define EPB1 5000      // edges per bucket1 block (320*5000 = 1.6M)
#define WPREP_BLKS 217 // wprep blocks inside k_wb1
#define GEMM_BLKS 782  // gemm1 blocks inside k_g1b2
#define B2BLK 392      // bucket2 half-bucket blocks (2 per bucket)
#define B2CAP 8192     // es capacity per half-bucket (avg 4096)

typedef short short8 __attribute__((ext_vector_type(8)));
typedef float f32x4 __attribute__((ext_vector_type(4)));
typedef _Float16 half8 __attribute__((ext_vector_type(8)));
typedef unsigned char uchar;

// ---- dtype helpers (isf32: 1 = buffers are fp32, 0 = bf16) ----
__device__ __forceinline__ float bf2f(ushort u) {
    union { unsigned u; float f; } x; x.u = ((unsigned)u) << 16; return x.f;
}
__device__ __forceinline__ ushort f2bf(float f) {
    union { float f; unsigned u; } x; x.f = f;
    unsigned r = x.u + 0x7FFF + ((x.u >> 16) & 1);   // RNE
    return (ushort)(r >> 16);
}
__device__ __forceinline__ float ldf(const void* p, size_t i, int isf32) {
    return isf32 ? ((const float*)p)[i] : bf2f(((const ushort*)p)[i]);
}
__device__ __forceinline__ void splitbf(float f, ushort& hi, ushort& lo) {
    unsigned u = __float_as_uint(f);
    unsigned uh = u & 0xFFFF0000u;
    hi = (ushort)(uh >> 16);
    lo = f2bf(f - __uint_as_float(uh));
}

// ---------------- workspace layout (bytes) ----------------
#define O_ROWPTR   0            // int[50001]
#define O_GCUR     200064       // int[196] per-bucket cursors
#define O_FLAGS    602240
#define O_ESRC     2202624      // ushort[1600000] CSR edge srcs
#define O_W1HI     5402624      // 144x256 bf16
#define O_W1LO     5476352
#define O_W2HI     5550080      // 144x128 bf16
#define O_W2LO     5586944
#define O_B1F      5623808
#define O_B2F      5624320
#define O_FEATG    5624832      // fp16 [N][128] layer-1 features
#define O_EL       18424832
#define O_ER       20024832
#define O_FEATG2   21624832     // fp16 [N][128] layer-2 features
#define O_EL2      34424832
#define O_ER2      36024832
// end: 37624832 (37.6 MB)
// alias inside O_FEATG2 (12.8 MB), dead before agg1m writes featg2:
#define O_PKBUF    O_FEATG2     // uint[196][12288] = 9.63 MB packed bucketed edges

// ================= device helpers =================

// ---- phase 0: zero bucket cursors (replaces hipMemsetAsync; graph-capture-safe) ----
__global__ __launch_bounds__(256) void k_zero(int* __restrict__ gcur) {
    int t = threadIdx.x;
    if (t < NB) gcur[t] = 0;
}

// inline dtype detect: scans W1's first 64KB as bf16, checks for huge exponents (fp32 pattern)
__device__ __forceinline__ int detect_isf32(const ushort* __restrict__ w1, int* smflag) {
    int t = threadIdx.x;
    if (t == 0) *smflag = 0;
    __syncthreads();
    int cnt = 0;
    for (int i = t; i < 32768; i += 256) {
        int e = (w1[i] >> 7) & 0xFF;
        if (e >= 0xC8) cnt++;
    }
    if (cnt > 0) *smflag = 1;    // benign race: all writers store 1
    __syncthreads();
    return *smflag;
}

// W -> whi/wlo bf16 [144][K] transposed (rows 0..127 = W cols, 128..135 = W@al, 136..143 = W@ar)
__device__ __forceinline__ void wprep_elem(const void* W, const void* al, const void* ar,
                                           int K, int kshift, ushort* whi, ushort* wlo,
                                           int isf32, int idx) {
    if (idx >= 144 * K) return;
    int n = idx >> kshift, k = idx & (K - 1);
    float f;
    if (n < 128) {
        f = ldf(W, (size_t)k * 128 + n, isf32);
    } else if (n < 136) {
        int h = n - 128;
        f = 0.f;
#pragma unroll
        for (int d = 0; d < HDIM; ++d)
            f = fmaf(ldf(W, (size_t)k * 128 + h * 16 + d, isf32), ldf(al, h * 16 + d, isf32), f);
    } else {
        int h = n - 136;
        f = 0.f;
#pragma unroll
        for (int d = 0; d < HDIM; ++d)
            f = fmaf(ldf(W, (size_t)k * 128 + h * 16 + d, isf32), ldf(ar, h * 16 + d, isf32), f);
    }
    ushort hi = f2bf(f);
    wlo[n * K + k] = f2bf(f - bf2f(hi));
    whi[n * K + k] = hi;
}

// block-level inclusive scan helper over sm[256]
__device__ __forceinline__ void block_scan(int* sm, int t) {
    for (int off = 1; off < 256; off <<= 1) {
        int v = (t >= off) ? sm[t - off] : 0;
        __syncthreads();
        sm[t] += v;
        __syncthreads();
    }
}

// LDS budget for the wprep||bucket1 union kernel: bucket1 needs 28376 B.
#define B1_SMEM 28384

// ---- phase A: wprep+inline-detect (blocks 0..216) || bucket1 (blocks 217..536) ----
// gcur pre-zeroed by k_zero. Block 216 publishes flags[0] for downstream kernels.
__global__ __launch_bounds__(256) void k_wb1(const void* __restrict__ W1, const void* __restrict__ al1,
                                             const void* __restrict__ ar1, const void* __restrict__ b1,
                                             const void* __restrict__ W2, const void* __restrict__ al2,
                                             const void* __restrict__ ar2, const void* __restrict__ b2,
                                             ushort* __restrict__ w1hi, ushort* __restrict__ w1lo,
                                             ushort* __restrict__ w2hi, ushort* __restrict__ w2lo,
                                             float* __restrict__ b1f, float* __restrict__ b2f,
                                             const int4* __restrict__ src4, const int4* __restrict__ dst4,
                                             int* __restrict__ gcur, uint* __restrict__ pkbuf,
                                             int* __restrict__ flags) {
    __shared__ __align__(16) char smem[B1_SMEM];
    int b = blockIdx.x, t = threadIdx.x;
    if (b < WPREP_BLKS) {
        int isf32 = detect_isf32((const ushort*)W1, (int*)smem);
        if (b < 144) {
            wprep_elem(W1, al1, ar1, 256, 8, w1hi, w1lo, isf32, b * 256 + t);
        } else if (b < 216) {
            wprep_elem(W2, al2, ar2, 128, 7, w2hi, w2lo, isf32, (b - 144) * 256 + t);
        } else {
            if (t < 128) b1f[t] = ldf(b1, t, isf32);
            else b2f[t - 128] = ldf(b2, t - 128, isf32);
            if (t == 0) flags[0] = isf32;
        }
    } else {
        uint*  stage = (uint*)smem;                  // 5000 uint  = 20000
        uchar* bid   = (uchar*)(smem + 20000);       // 5000 uchar = 5000
        uint*  cnt   = (uint*)(smem + 25000);        // 784
        int*   loff  = (int*)(smem + 25784);         // 784
        int*   goff  = (int*)(smem + 26568);         // 784
        int*   sm    = (int*)(smem + 27352);         // 1024 -> 28376
        int bb = b - WPREP_BLKS;
        for (int w = t; w < NB; w += 256) cnt[w] = 0;
        __syncthreads();
        int base4 = bb * (EPB1 / 4);
        // pass 1: count buckets
        for (int g = t; g < EPB1 / 4; g += 256) {
            int4 d = dst4[base4 + g];
            atomicAdd(&cnt[d.x >> 8], 1u);
            atomicAdd(&cnt[d.y >> 8], 1u);
            atomicAdd(&cnt[d.z >> 8], 1u);
            atomicAdd(&cnt[d.w >> 8], 1u);
        }
        __syncthreads();
        int c = (t < NB) ? (int)cnt[t] : 0;
        sm[t] = c;
        __syncthreads();
        block_scan(sm, t);
        if (t < NB) {
            loff[t] = sm[t] - c;                       // exclusive local offset
            goff[t] = atomicAdd(&gcur[t], c);          // reserve global space
            cnt[t] = 0;                                // reset for rank pass
        }
        __syncthreads();
        // pass 2: scatter into LDS stage sorted by bucket, record bucket id
        for (int g = t; g < EPB1 / 4; g += 256) {
            int4 s = src4[base4 + g];
            int4 d = dst4[base4 + g];
            { int bk = d.x >> 8; int r = atomicAdd(&cnt[bk], 1u); int p = loff[bk] + r; stage[p] = ((uint)s.x << 8) | (uint)(d.x & 255); bid[p] = (uchar)bk; }
            { int bk = d.y >> 8; int r = atomicAdd(&cnt[bk], 1u); int p = loff[bk] + r; stage[p] = ((uint)s.y << 8) | (uint)(d.y & 255); bid[p] = (uchar)bk; }
            { int bk = d.z >> 8; int r = atomicAdd(&cnt[bk], 1u); int p = loff[bk] + r; stage[p] = ((uint)s.z << 8) | (uint)(d.z & 255); bid[p] = (uchar)bk; }
            { int bk = d.w >> 8; int r = atomicAdd(&cnt[bk], 1u); int p = loff[bk] + r; stage[p] = ((uint)s.w << 8) | (uint)(d.w & 255); bid[p] = (uchar)bk; }
        }
        __syncthreads();
        // pass 3: one linear loop, per-element direct destination
        for (int k = t; k < EPB1; k += 256) {
            int bk = (int)bid[k];
            int gi = goff[bk] + (k - loff[bk]);
            if (gi < BCAP) pkbuf[(size_t)bk * BCAP + gi] = stage[k];
        }
    }
}

// coalesced featg tile store via per-wave LDS region
__device__ __forceinline__ void store_tile(_Float16 (*sfe)[72], _Float16* featg,
                                           const f32x4* acc, int lane, int quad, int l16,
                                           int rowb0, int cbase) {
#pragma unroll
    for (int ci = 0; ci < 4; ++ci)
#pragma unroll
        for (int r = 0; r < 4; ++r)
            sfe[quad * 4 + r][ci * 16 + l16] = (_Float16)acc[ci][r];
    int rr = lane >> 3, ch = lane & 7;
#pragma unroll
    for (int s = 0; s < 2; ++s) {
        int row = s * 8 + rr;
        short8 v = *(const short8*)&sfe[row][ch * 8];
        *(short8*)(featg + (size_t)(rowb0 + row) * D1 + cbase * 16 + ch * 8) = v;
    }
}

// gemm1, 9 c-tiles per wave (A fetched ONCE into registers)
__device__ __forceinline__ void gemm1_wave9(const void* A, const ushort* Bhi, const ushort* Blo,
                                            _Float16* featg, float* el, float* er,
                                            int isf32, int rt, int lane, _Float16 (*sfe)[72]) {
    int quad = lane >> 4, l16 = lane & 15;
    const int K = 256;
    size_t a_off = (size_t)(rt * 16 + l16) * K + quad * 8;
    int rowb0 = rt * 16;

    short8 ahi[8], alo[8];
    if (isf32) {
        const float* ap = (const float*)A + a_off;
#pragma unroll
        for (int i = 0; i < 8; ++i) {
            f32x4 u0 = *(const f32x4*)(ap + 32 * i);
            f32x4 u1 = *(const f32x4*)(ap + 32 * i + 4);
            float a8[8] = {u0[0], u0[1], u0[2], u0[3], u1[0], u1[1], u1[2], u1[3]};
#pragma unroll
            for (int j = 0; j < 8; ++j) {
                ushort h, l;
                splitbf(a8[j], h, l);
                ahi[i][j] = (short)h; alo[i][j] = (short)l;
            }
        }
    } else {
        const ushort* ap = (const ushort*)A + a_off;
#pragma unroll
        for (int i = 0; i < 8; ++i) ahi[i] = *(const short8*)(ap + 32 * i);
    }

#pragma unroll
    for (int g = 0; g < 2; ++g) {
        f32x4 acc[4];
#pragma unroll
        for (int ci = 0; ci < 4; ++ci) acc[ci] = (f32x4){0.f, 0.f, 0.f, 0.f};
#pragma unroll
        for (int ci = 0; ci < 4; ++ci) {
            int c = g * 4 + ci;
            const ushort* bh = Bhi + (size_t)(c * 16 + l16) * K + quad * 8;
            if (isf32) {
                const ushort* bl = Blo + (size_t)(c * 16 + l16) * K + quad * 8;
#pragma unroll
                for (int k = 0; k < 8; ++k) {
                    short8 bh8 = *(const short8*)(bh + 32 * k);
                    short8 bl8 = *(const short8*)(bl + 32 * k);
                    acc[ci] = __builtin_amdgcn_mfma_f32_16x16x32_bf16(ahi[k], bh8, acc[ci], 0, 0, 0);
                    acc[ci] = __builtin_amdgcn_mfma_f32_16x16x32_bf16(ahi[k], bl8, acc[ci], 0, 0, 0);
                    acc[ci] = __builtin_amdgcn_mfma_f32_16x16x32_bf16(alo[k], bh8, acc[ci], 0, 0, 0);
                }
            } else {
#pragma unroll
                for (int k = 0; k < 8; ++k) {
                    short8 bh8 = *(const short8*)(bh + 32 * k);
                    acc[ci] = __builtin_amdgcn_mfma_f32_16x16x32_bf16(ahi[k], bh8, acc[ci], 0, 0, 0);
                }
            }
        }
        store_tile(sfe, featg, acc, lane, quad, l16, rowb0, g * 4);
    }

    // el/er fold tile (c=8)
    {
        const ushort* bh = Bhi + (size_t)(8 * 16 + l16) * K + quad * 8;
        const ushort* bl = Blo + (size_t)(8 * 16 + l16) * K + quad * 8;
        f32x4 a = {0.f, 0.f, 0.f, 0.f};
#pragma unroll
        for (int k = 0; k < 8; ++k) {
            short8 bh8 = *(const short8*)(bh + 32 * k);
            short8 bl8 = *(const short8*)(bl + 32 * k);
            a = __builtin_amdgcn_mfma_f32_16x16x32_bf16(ahi[k], bh8, a, 0, 0, 0);
            a = __builtin_amdgcn_mfma_f32_16x16x32_bf16(ahi[k], bl8, a, 0, 0, 0);
            if (isf32) a = __builtin_amdgcn_mfma_f32_16x16x32_bf16(alo[k], bh8, a, 0, 0, 0);
        }
#pragma unroll
        for (int r = 0; r < 4; ++r) {
            int row = rowb0 + quad * 4 + r;
            if (l16 < 8) el[row * 8 + l16] = a[r];
            else         er[row * 8 + (l16 - 8)] = a[r];
        }
    }
}

// LDS budget for gemm||bucket2 union: half-bucket bucket2 needs 19456 B; gemm needs 9216.
// 160KB / 19.5KB = 8 blocks/CU = gemm's wave cap -> no occupancy loss for gemm.
#define G1B2_SMEM 19456

// ---- phase B: gemm1 (blocks 0..781) || bucket2 half-bucket (blocks 782..1173) ----
__global__ __launch_bounds__(256) void k_g1b2(const void* __restrict__ A,
                                              const ushort* __restrict__ w1hi, const ushort* __restrict__ w1lo,
                                              _Float16* __restrict__ featg,
                                              float* __restrict__ el, float* __restrict__ er,
                                              const uint* __restrict__ pkbuf, const int* __restrict__ gcur,
                                              ushort* __restrict__ esrc, int* __restrict__ rowptr,
                                              const int* __restrict__ flags) {
    __shared__ __align__(16) char smem[G1B2_SMEM];
    int b = blockIdx.x, t = threadIdx.x;
    if (b < GEMM_BLKS) {
        _Float16 (*sfe4)[16][72] = (_Float16(*)[16][72])smem;
        int wave = t >> 6, lane = t & 63;
        int rt = b * 4 + wave;
        if (rt < RTILES)
            gemm1_wave9(A, w1hi, w1lo, featg, el, er, flags[0], rt, lane, sfe4[wave]);
    } else {
        ushort* es    = (ushort*)smem;                 // 8192*2 = 16384
        uint*   ncnt  = (uint*)(smem + 16384);         // 1024
        int*    sm    = (int*)(smem + 17408);          // 1024
        int*    nbase = (int*)(smem + 18432);          // 1024 -> 19456
        int bb = b - GEMM_BLKS;
        int bk = bb >> 1, half = bb & 1;
        // scan gcur for bucket base
        int x = (t < NB) ? gcur[t] : 0;
        sm[t] = x;
        __syncthreads();
        block_scan(sm, t);
        int nb = gcur[bk]; if (nb > BCAP) nb = BCAP;
        int bb0 = sm[bk] - gcur[bk];
        if (bb == 0 && t == NB - 1) rowptr[N_NODES] = sm[t];
        __syncthreads();
        ncnt[t] = 0;
        __syncthreads();
        const uint* pbase = pkbuf + (size_t)bk * BCAP;
        // count pass (all 256 nodes of the bucket)
        for (int k = t; k < nb; k += 256)
            atomicAdd(&ncnt[pbase[k] & 255u], 1u);
        __syncthreads();
        int c = (int)ncnt[t];
        sm[t] = c;
        __syncthreads();
        block_scan(sm, t);
        nbase[t] = sm[t] - c;                          // exclusive prefix within bucket
        int v = bk * 256 + t;
        if (v < N_NODES && (t >> 7) == half) rowptr[v] = bb0 + sm[t] - c;
        ncnt[t] = 0;                                   // reset for rank pass
        __syncthreads();
        int lo = half * 128, hi = lo + 128;
        int base0 = nbase[lo];
        // scatter my half's edges into LDS image (re-read pkbuf from L2)
        for (int k = t; k < nb; k += 256) {
            uint u = pbase[k];
            int n = (int)(u & 255u);
            if (n >= lo && n < hi) {
                int r = (int)atomicAdd(&ncnt[n], 1u);
                int p = nbase[n] + r - base0;
                if (p >= 0 && p < B2CAP) es[p] = (ushort)(u >> 8);
            }
        }
        __syncthreads();
        int myedges = sm[hi - 1] - base0;
        if (myedges > B2CAP) myedges = B2CAP;
        // stream out coalesced
        for (int k = t; k < myedges; k += 256)
            esrc[bb0 + base0 + k] = es[k];
    }
}

// ---- wide gather core (round-5 v1, measured 93.6us): per 8-edge batch, 2x half8 row-gathers ----
// Lane roles: h8=lane&7/esel=lane>>3 compute w(edge=esel, head=h8);
// part=lane&15 owns channels part*8..+7 (head part>>1); a=lane>>4 owns edges {a, a+4}.
__device__ __forceinline__ void gather_wide(const int* __restrict__ rowptr, const ushort* __restrict__ esrc,
                                            const _Float16* __restrict__ featg,
                                            const float* __restrict__ el, const float* __restrict__ er,
                                            int v, int lane, float (&acc)[8], float& den, int& deg) {
    int h8 = lane & 7, esel = lane >> 3;
    int part = lane & 15, a = lane >> 4, hpart = part >> 1;
    float erv = er[v * 8 + h8];
    int beg = rowptr[v], end = rowptr[v + 1];
    deg = end - beg;
#pragma unroll
    for (int c = 0; c < 8; ++c) acc[c] = 0.f;
    den = 0.f;
    for (int j = beg; j < end; j += 8) {
        int nv = end - j;                       // edges valid this batch (>=1)
        int idx = j + h8; if (idx >= end) idx = end - 1;
        int sv = (int)esrc[idx];
        int se = __shfl(sv, esel);
        float x = el[se * 8 + h8] + erv;
        x = x > 0.f ? x : NEG_SLOPE * x;
        float w = __expf(x);
        if (esel >= nv) w = 0.f;                // invalid edges contribute nothing
        int s0 = __shfl(sv, a);
        int s1 = __shfl(sv, a + 4);
        half8 g0 = *(const half8*)(featg + (size_t)s0 * 128 + part * 8);
        half8 g1 = *(const half8*)(featg + (size_t)s1 * 128 + part * 8);
        float w0 = __shfl(w, a * 8 + hpart);
        float w1 = __shfl(w, (a + 4) * 8 + hpart);
        den += w0 + w1;
#pragma unroll
        for (int c = 0; c < 8; ++c)
            acc[c] = fmaf(w0, (float)g0[c], fmaf(w1, (float)g1[c], acc[c]));
    }
    // merge edge-slots (lane bits 4,5)
#pragma unroll
    for (int c = 0; c < 8; ++c) {
        acc[c] += __shfl_xor(acc[c], 16);
        acc[c] += __shfl_xor(acc[c], 32);
    }
    den += __shfl_xor(den, 16);
    den += __shfl_xor(den, 32);
}

// ---- phase C: agg layer 1 (wide gather) + fused MFMA dense (layer-2 transform) ----
__global__ __launch_bounds__(256) void k_agg1m(const int* __restrict__ rowptr, const ushort* __restrict__ esrc,
                                               const _Float16* __restrict__ featg,
                                               const float* __restrict__ el, const float* __restrict__ er,
                                               const float* __restrict__ b1f,
                                               const ushort* __restrict__ w2hi, const ushort* __restrict__ w2lo,
                                               _Float16* __restrict__ featg2,
                                               float* __restrict__ el2, float* __restrict__ er2,
                                               const int* __restrict__ flags) {
    __shared__ __align__(16) ushort sh_hi[16][136];
    __shared__ __align__(16) ushort sh_lo[16][136];
    int isf32 = flags[0];
    int wave = threadIdx.x >> 6, lane = threadIdx.x & 63;
    int part = lane & 15, a = lane >> 4;
    int vb = blockIdx.x * 16;
    f32x4 bia0 = *(const f32x4*)(b1f + part * 8);
    f32x4 bia1 = *(const f32x4*)(b1f + part * 8 + 4);
#pragma unroll
    for (int i = 0; i < 4; ++i) {
        int v = vb + wave * 4 + i;
        float acc[8], den; int dg;
        gather_wide(rowptr, esrc, featg, el, er, v, lane, acc, den, dg);
        float inv = (dg > 0) ? 1.0f / den : 0.f;
        if (a == 0) {
            short8 hi8, lo8;
#pragma unroll
            for (int c = 0; c < 8; ++c) {
                float bc = (c < 4) ? bia0[c] : bia1[c - 4];
                float r = fmaf(acc[c], inv, bc);
                r = r > 0.f ? r : (__expf(r) - 1.f);   // ELU
                ushort h, l;
                splitbf(r, h, l);
                hi8[c] = (short)h; lo8[c] = (short)l;
            }
            int m = wave * 4 + i;
            *(short8*)&sh_hi[m][part * 8] = hi8;
            *(short8*)&sh_lo[m][part * 8] = lo8;
        }
    }
    __syncthreads();

    // MFMA epilogue: y = h @ W2ext (K=128)
    int quad = lane >> 4, l16 = lane & 15;
    const int K = 128;
    short8 ahi[4], alo[4];
#pragma unroll
    for (int k = 0; k < 4; ++k) {
        ahi[k] = *(const short8*)&sh_hi[l16][quad * 8 + 32 * k];
        alo[k] = *(const short8*)&sh_lo[l16][quad * 8 + 32 * k];
    }
    int ntile = (wave == 0) ? 3 : 2;
    for (int ti = 0; ti < ntile; ++ti) {
        int c = (ti == 2) ? 8 : wave + ti * 4;
        const ushort* bh = w2hi + (size_t)(c * 16 + l16) * K + quad * 8;
        const ushort* bl = w2lo + (size_t)(c * 16 + l16) * K + quad * 8;
        f32x4 aa = {0.f, 0.f, 0.f, 0.f};
#pragma unroll
        for (int k = 0; k < 4; ++k) {
            short8 bh8 = *(const short8*)(bh + 32 * k);
            aa = __builtin_amdgcn_mfma_f32_16x16x32_bf16(ahi[k], bh8, aa, 0, 0, 0);
            aa = __builtin_amdgcn_mfma_f32_16x16x32_bf16(alo[k], bh8, aa, 0, 0, 0);
            if (c == 8 || isf32) {
                short8 bl8 = *(const short8*)(bl + 32 * k);
                aa = __builtin_amdgcn_mfma_f32_16x16x32_bf16(ahi[k], bl8, aa, 0, 0, 0);
            }
        }
        if (c < 8) {
#pragma unroll
            for (int r = 0; r < 4; ++r)
                featg2[(size_t)(vb + quad * 4 + r) * D1 + c * 16 + l16] = (_Float16)aa[r];
        } else {
#pragma unroll
            for (int r = 0; r < 4; ++r) {
                int row = vb + quad * 4 + r;
                if (l16 < 8) el2[row * 8 + l16] = aa[r];
                else         er2[row * 8 + (l16 - 8)] = aa[r];
            }
        }
    }
}

// ---- phase D: agg layer 2 (wide gather) -> head-mean -> d_out ----
__global__ __launch_bounds__(256) void k_agg2(const int* __restrict__ rowptr, const ushort* __restrict__ esrc,
                                              const _Float16* __restrict__ featg2,
                                              const float* __restrict__ el2, const float* __restrict__ er2,
                                              const float* __restrict__ b2f,
                                              void* __restrict__ out, const int* __restrict__ flags) {
    int wave = threadIdx.x >> 6, lane = threadIdx.x & 63;
    int v = blockIdx.x * 4 + wave;
    if (v >= N_NODES) return;
    int part = lane & 15;
    float acc[8], den; int dg;
    gather_wide(rowptr, esrc, featg2, el2, er2, v, lane, acc, den, dg);
    float inv = (dg > 0) ? 1.0f / den : 0.f;
    f32x4 bia0 = *(const f32x4*)(b2f + part * 8);
    f32x4 bia1 = *(const f32x4*)(b2f + part * 8 + 4);
    float r[8];
#pragma unroll
    for (int c = 0; c < 8; ++c) {
        float bc = (c < 4) ? bia0[c] : bia1[c - 4];
        r[c] = fmaf(acc[c], inv, bc);
    }
    // head-mean: sum over part bits 1..3 (head index)
#pragma unroll
    for (int c = 0; c < 8; ++c) {
        r[c] += __shfl_xor(r[c], 2);
        r[c] += __shfl_xor(r[c], 4);
        r[c] += __shfl_xor(r[c], 8);
        r[c] *= 0.125f;
    }
    if (lane < 2) {
        if (flags[0]) {
            float* op = (float*)out + (size_t)v * 16 + lane * 8;
            f32x4 o0 = {r[0], r[1], r[2], r[3]};
            f32x4 o1 = {r[4], r[5], r[6], r[7]};
            *(f32x4*)op = o0;
            *(f32x4*)(op + 4) = o1;
        } else {
            short8 pk;
#pragma unroll
            for (int c = 0; c < 8; ++c) pk[c] = (short)f2bf(r[c]);
            *(short8*)((ushort*)out + (size_t)v * 16 + lane * 8) = pk;
        }
    }
}

extern "C" void kernel_launch(void* const* d_in, const int* in_sizes, int n_in,
                              void* d_out, int out_size, void* d_ws, size_t ws_size,
                              hipStream_t stream) {
    const void* node_feat = d_in[0];
    const int4* src4 = (const int4*)d_in[1];
    const int4* dst4 = (const int4*)d_in[2];
    const void* W1 = d_in[3];
    const void* al1 = d_in[4];
    const void* ar1 = d_in[5];
    const void* b1 = d_in[6];
    const void* W2 = d_in[7];
    const void* al2 = d_in[8];
    const void* ar2 = d_in[9];
    const void* b2 = d_in[10];
    char* ws = (char*)d_ws;

    int* rowptr = (int*)(ws + O_ROWPTR);
    int* gcur   = (int*)(ws + O_GCUR);
    int* flags  = (int*)(ws + O_FLAGS);
    ushort* esrc = (ushort*)(ws + O_ESRC);
    uint* pkbuf = (uint*)(ws + O_PKBUF);
    ushort* w1hi = (ushort*)(ws + O_W1HI);
    ushort* w1lo = (ushort*)(ws + O_W1LO);
    ushort* w2hi = (ushort*)(ws + O_W2HI);
    ushort* w2lo = (ushort*)(ws + O_W2LO);
    float* b1f  = (float*)(ws + O_B1F);
    float* b2f  = (float*)(ws + O_B2F);
    _Float16* featg = (_Float16*)(ws + O_FEATG);
    float* el   = (float*)(ws + O_EL);
    float* er   = (float*)(ws + O_ER);
    _Float16* featg2 = (_Float16*)(ws + O_FEATG2);
    float* el2  = (float*)(ws + O_EL2);
    float* er2  = (float*)(ws + O_ER2);

    // 0: zero bucket cursors (kernel, graph-capture-safe)
    k_zero<<<1, 256, 0, stream>>>(gcur);
    // A: wprep (inline dtype detect; block 216 publishes flags) || bucket1
    k_wb1<<<WPREP_BLKS + B1BLK, 256, 0, stream>>>(W1, al1, ar1, b1, W2, al2, ar2, b2,
                                                  w1hi, w1lo, w2hi, w2lo, b1f, b2f,
                                                  src4, dst4, gcur, pkbuf, flags);
    // B: gemm1 || bucket2 (half-bucket, slim LDS)
    k_g1b2<<<GEMM_BLKS + B2BLK, 256, 0, stream>>>(node_feat, w1hi, w1lo, featg, el, er,
                                                  pkbuf, gcur, esrc, rowptr, flags);
    // C: agg layer 1 (wide v1) + fused MFMA dense
    k_agg1m<<<N_NODES / 16, 256, 0, stream>>>(rowptr, esrc, featg, el, er, b1f,
                                              w2hi, w2lo, featg2, el2, er2, flags);
    // D: agg layer 2 (wide v1) -> output
    k_agg2<<<(N_NODES + 3) / 4, 256, 0, stream>>>(rowptr, esrc, featg2, el2, er2,
                                                  b2f, d_out, flags);
}